// Round 1
// baseline (204.725 us; speedup 1.0000x reference)
//
#include <hip/hip_runtime.h>
#include <math.h>

#define ALPHA 0.2f
#define BETA 1.0f
#define EPSV 1e-8f
#define LOG2E 1.4426950408889634f
#define LN2 0.6931471805599453f

#define BATCH 4096
#define RR 18
#define KT 17            // R-1 targets per row
#define DD 256
#define NTGT (BATCH*KT)  // 69632 total targets

#define BMW 64           // anchors per wave (2 x 32-tiles, frags in registers)
#define NWAVES 4
#define BMB (BMW*NWAVES) // 256 anchors per block
#define MBLK (BATCH/BMB) // 16
#define BN 64            // targets per LDS chunk
#define NSPLIT 136       // N-dimension splits (grid 2176 = ~8.5 blocks/CU queued)
#define NSLOT NSPLIT     // per-anchor partial slots (half-waves merged in-reg)
#define NSLICE (NTGT/NSPLIT) // 512
#define NCHUNK (NSLICE/BN)   // 8
#define CHUNK_BYTES (BN*DD)  // 16384 fp8 bytes, fragment-ordered

// Schraudolph fast exp2: 2^d ~= bitcast(u32(d*2^23 + KBIAS)), d<=0.
// KBIAS = 127*2^23 - 472890 (zero-mean multiplicative error, +-4%).
// v_cvt_u32_f32 saturates negatives to 0 -> free underflow clamp.
#define EXPA 8388608.0f
#define EXPB 1064880320.0f

typedef int   i32x8  __attribute__((ext_vector_type(8)));
typedef float f32x16 __attribute__((ext_vector_type(16)));

__device__ inline void gl_lds16(const void* g, void* l){
  __builtin_amdgcn_global_load_lds(
      (const __attribute__((address_space(1))) unsigned int*)g,
      (__attribute__((address_space(3))) unsigned int*)l, 16, 0, 0);
}

__device__ inline int pk8(float a, float b, float c, float d){
  int p = __builtin_amdgcn_cvt_pk_fp8_f32(a, b, 0, false);
  return  __builtin_amdgcn_cvt_pk_fp8_f32(c, d, p, true);
}

__device__ inline float fmax3(float a, float b, float c){
  return fmaxf(fmaxf(a, b), c);   // clang fuses to v_max3_f32
}

__device__ inline float fexp2u(float x, float kc){
  float t = fmaf(x, EXPA, kc);
  unsigned u;
  asm("v_cvt_u32_f32 %0, %1" : "=v"(u) : "v"(t));   // saturating: t<0 -> 0
  return __uint_as_float(u);
}

// tbf8 fragment layout (fp8 e4m3): target t -> chunk c=t>>6, r=t&63,
// mt=r>>5, m=r&31.  K split: ki=k>>6 (4), half=(k>>5)&1, w=(k>>4)&1.
// 1-KB region (ki*2+mt)*2+w inside chunk; 16-B slot (half*32+m).
// Gemm lane l (m=l&31, half=l>>5) reads lane-linear -> conflict-free b128.

// ---------------- Kernel 1: convert->fp8 + KL + diag -------------------------
// 256 threads = 16 groups of 16 lanes; group g handles target rows g+1, g+17.
// Each lane owns 16 contiguous k (one 16-B fp8 fragment slot) -> direct store.
__global__ __launch_bounds__(256) void prep_kernel(
    const float* __restrict__ feat, const float* __restrict__ scores,
    const float* __restrict__ lscale,
    unsigned char* __restrict__ abf8, unsigned char* __restrict__ tbf8,
    float* __restrict__ diag, float* __restrict__ klarr){
  __shared__ float csh[KT];
  int b = blockIdx.x, tid = threadIdx.x;
  int grp = tid >> 4, j = tid & 15;
  const float* fb = feat + (size_t)b * RR * DD;
  float s2 = lscale[0] * LOG2E;

  // anchor: each lane loads its 16 k-values (same across groups -> L1 broadcast)
  float4 a0 = ((const float4*)fb)[j*4+0];
  float4 a1 = ((const float4*)fb)[j*4+1];
  float4 a2 = ((const float4*)fb)[j*4+2];
  float4 a3 = ((const float4*)fb)[j*4+3];
  float asq = (a0.x*a0.x+a0.y*a0.y+a0.z*a0.z+a0.w*a0.w)
            + (a1.x*a1.x+a1.y*a1.y+a1.z*a1.z+a1.w*a1.w)
            + (a2.x*a2.x+a2.y*a2.y+a2.z*a2.z+a2.w*a2.w)
            + (a3.x*a3.x+a3.y*a3.y+a3.z*a3.z+a3.w*a3.w);
  #pragma unroll
  for (int off=1; off<16; off<<=1) asq += __shfl_xor(asq, off);
  float an = fmaxf(sqrtf(asq), EPSV);

  if (tid < 16){   // anchor fp8 out (scaled into log2 domain), 16 B per lane
    uint4 v = make_uint4(
      (unsigned)pk8(a0.x*s2,a0.y*s2,a0.z*s2,a0.w*s2),
      (unsigned)pk8(a1.x*s2,a1.y*s2,a1.z*s2,a1.w*s2),
      (unsigned)pk8(a2.x*s2,a2.y*s2,a2.z*s2,a2.w*s2),
      (unsigned)pk8(a3.x*s2,a3.y*s2,a3.z*s2,a3.w*s2));
    *(uint4*)(abf8 + (size_t)b*DD + j*16) = v;
  }

  for (int kr = grp+1; kr <= KT; kr += 16){
    const float4* tp = (const float4*)(fb + (size_t)kr*DD) + j*4;
    float4 t0=tp[0], t1=tp[1], t2=tp[2], t3=tp[3];
    // fp8 fragment store: lane j holds k in [j*16, j*16+16)
    int t  = b*KT + (kr-1);
    int c  = t >> 6, r = t & 63, mt = (r >> 5) & 1, m = r & 31;
    int ki = j >> 2, hf = (j >> 1) & 1, w = j & 1;
    uint4 v = make_uint4(
      (unsigned)pk8(t0.x,t0.y,t0.z,t0.w), (unsigned)pk8(t1.x,t1.y,t1.z,t1.w),
      (unsigned)pk8(t2.x,t2.y,t2.z,t2.w), (unsigned)pk8(t3.x,t3.y,t3.z,t3.w));
    *(uint4*)(tbf8 + (size_t)c*CHUNK_BYTES + (size_t)((ki*2+mt)*2+w)*1024
              + hf*512 + m*16) = v;
    float d = (a0.x*t0.x+a0.y*t0.y+a0.z*t0.z+a0.w*t0.w)
            + (a1.x*t1.x+a1.y*t1.y+a1.z*t1.z+a1.w*t1.w)
            + (a2.x*t2.x+a2.y*t2.y+a2.z*t2.z+a2.w*t2.w)
            + (a3.x*t3.x+a3.y*t3.y+a3.z*t3.z+a3.w*t3.w);
    float q = (t0.x*t0.x+t0.y*t0.y+t0.z*t0.z+t0.w*t0.w)
            + (t1.x*t1.x+t1.y*t1.y+t1.z*t1.z+t1.w*t1.w)
            + (t2.x*t2.x+t2.y*t2.y+t2.z*t2.z+t2.w*t2.w)
            + (t3.x*t3.x+t3.y*t3.y+t3.z*t3.z+t3.w*t3.w);
    #pragma unroll
    for (int off=1; off<16; off<<=1){ d += __shfl_xor(d,off); q += __shfl_xor(q,off); }
    if (j == 0){
      csh[kr-1] = d / (an * fmaxf(sqrtf(q), EPSV));
      if (kr == 1) diag[b] = d;
    }
  }
  __syncthreads();

  // KL over KT=17 entries, wave-parallel on wave 0 (lanes >= KT padded)
  if (tid < 64){
    bool act = tid < KT;
    float c  = act ? csh[tid] : -INFINITY;
    float sv = act ? scores[(size_t)b*KT + tid] : -INFINITY;
    float cm = c, sm = sv;
    #pragma unroll
    for (int off=1; off<64; off<<=1){
      cm = fmaxf(cm, __shfl_xor(cm, off));
      sm = fmaxf(sm, __shfl_xor(sm, off));
    }
    float ec = act ? __builtin_amdgcn_exp2f((c -cm)*LOG2E) : 0.f;
    float es = act ? __builtin_amdgcn_exp2f((sv-sm)*LOG2E) : 0.f;
    float cs = ec, ss = es;
    #pragma unroll
    for (int off=1; off<64; off<<=1){
      cs += __shfl_xor(cs, off);
      ss += __shfl_xor(ss, off);
    }
    float lse_c = cm + __logf(cs);
    float lse_s = sm + __logf(ss);
    float kt = 0.f;
    if (act){
      float lq = sv - lse_s;
      float lp = c  - lse_c;
      kt = __builtin_amdgcn_exp2f(lq*LOG2E)*(lq - lp);
    }
    #pragma unroll
    for (int off=1; off<64; off<<=1) kt += __shfl_xor(kt, off);
    if (tid == 0) klarr[b] = kt * (1.0f/KT);
  }
}

// ---------------- Kernel 2: MX-fp8 32x32x64 MFMA + online log2-sum-exp2 ------
// D[m=target][n=anchor], scales=1.0 (e8m0 127). Double-buffered LDS, one
// barrier per chunk. Epilogue uses full-rate Schraudolph exp2 (fma+cvt+add)
// instead of trans-pipe v_exp_f32; per-chunk max folded into the fma bias.
__global__ __launch_bounds__(256,3) void gemm_lse_kernel(
    const unsigned char* __restrict__ abf8, const unsigned char* __restrict__ tbf8,
    float* __restrict__ part_m, float* __restrict__ part_s){
  __shared__ __align__(16) unsigned char Bs[2][CHUNK_BYTES];   // 2 x 16 KB
  const int tid  = threadIdx.x;
  const int lane = tid & 63;
  const int wave = tid >> 6;
  const int mb   = blockIdx.y;
  const int ns   = blockIdx.x;
  const int l31  = lane & 31;
  const int half = lane >> 5;

  const char* gbase = (const char*)tbf8 + (size_t)(ns*NCHUNK)*CHUNK_BYTES;
  auto stage = [&](int ch){
    const char* g = gbase + (size_t)ch*CHUNK_BYTES;
    char* l = (char*)Bs[ch & 1];
    #pragma unroll
    for (int j=0;j<4;++j){
      int off = j*4096 + tid*16;
      gl_lds16(g + off, l + off);
    }
  };

  stage(0);   // DMA in flight while we fetch anchor frags

  // anchor B-operand frags (once per block): n=l31, k=half*32+byte, per ki
  i32x8 af[2][4];
  {
    const unsigned char* ab = abf8 + (size_t)(mb*BMB + wave*BMW)*DD;
    #pragma unroll
    for (int nt=0;nt<2;++nt)
      #pragma unroll
      for (int ki=0;ki<4;++ki){
        const unsigned char* p = ab + (size_t)(nt*32+l31)*DD + ki*64 + half*32;
        uint4 lo = *(const uint4*)p;
        uint4 hi = *(const uint4*)(p+16);
        af[nt][ki] = (i32x8){(int)lo.x,(int)lo.y,(int)lo.z,(int)lo.w,
                             (int)hi.x,(int)hi.y,(int)hi.z,(int)hi.w};
      }
  }

  float run_m[2] = {-INFINITY,-INFINITY};
  float run_s[2] = {0.f,0.f};

  for (int ch=0; ch<NCHUNK; ++ch){
    __syncthreads();                   // DMA for ch drained; buf[ch^1] reads done
    if (ch+1 < NCHUNK) stage(ch+1);    // async DMA into other buffer

    const unsigned char* frag = &Bs[ch & 1][0] + lane*16;

    f32x16 acc[2][2];
    #pragma unroll
    for (int mt=0;mt<2;++mt)
      #pragma unroll
      for (int nt=0;nt<2;++nt)
        acc[mt][nt] = (f32x16)(0.f);

    #pragma unroll
    for (int ki=0;ki<4;++ki){
      i32x8 tf[2];
      #pragma unroll
      for (int mt=0;mt<2;++mt){
        uint4 lo = *(const uint4*)(frag + (size_t)((ki*2+mt)*2+0)*1024);
        uint4 hi = *(const uint4*)(frag + (size_t)((ki*2+mt)*2+1)*1024);
        tf[mt] = (i32x8){(int)lo.x,(int)lo.y,(int)lo.z,(int)lo.w,
                         (int)hi.x,(int)hi.y,(int)hi.z,(int)hi.w};
      }
      acc[0][0] = __builtin_amdgcn_mfma_scale_f32_32x32x64_f8f6f4(
                      tf[0], af[0][ki], acc[0][0], 0,0, 0,127, 0,127);
      acc[0][1] = __builtin_amdgcn_mfma_scale_f32_32x32x64_f8f6f4(
                      tf[0], af[1][ki], acc[0][1], 0,0, 0,127, 0,127);
      acc[1][0] = __builtin_amdgcn_mfma_scale_f32_32x32x64_f8f6f4(
                      tf[1], af[0][ki], acc[1][0], 0,0, 0,127, 0,127);
      acc[1][1] = __builtin_amdgcn_mfma_scale_f32_32x32x64_f8f6f4(
                      tf[1], af[1][ki], acc[1][1], 0,0, 0,127, 0,127);
    }

    // epilogue (log2 domain): pure in-lane, per half-wave partials.
    #pragma unroll
    for (int nt=0;nt<2;++nt){
      f32x16 t = __builtin_elementwise_max(acc[0][nt], acc[1][nt]);
      float x0 = fmax3(t[0], t[1], t[2]);
      float x1 = fmax3(t[3], t[4], t[5]);
      float x2 = fmax3(t[6], t[7], t[8]);
      float x3 = fmax3(t[9], t[10], t[11]);
      float x4 = fmax3(t[12], t[13], t[14]);
      float mx = fmaxf(fmax3(x0,x1,x2), fmax3(x3,x4,t[15]));

      float kc = fmaf(mx, -EXPA, EXPB);   // fold -mx into Schraudolph bias
      float s0=0.f, s1=0.f, s2=0.f, s3=0.f;
      #pragma unroll
      for (int r=0;r<16;r+=4){
        s0 += fexp2u(acc[0][nt][r  ],kc) + fexp2u(acc[1][nt][r  ],kc);
        s1 += fexp2u(acc[0][nt][r+1],kc) + fexp2u(acc[1][nt][r+1],kc);
        s2 += fexp2u(acc[0][nt][r+2],kc) + fexp2u(acc[1][nt][r+2],kc);
        s3 += fexp2u(acc[0][nt][r+3],kc) + fexp2u(acc[1][nt][r+3],kc);
      }
      float sh = (s0+s1)+(s2+s3);

      float nm = fmaxf(run_m[nt], mx);
      run_s[nt] = run_s[nt]*__builtin_amdgcn_exp2f(run_m[nt]-nm)
                + sh*__builtin_amdgcn_exp2f(mx-nm);
      run_m[nt] = nm;
    }
  }

  // merge the two half-wave partials (disjoint target rows, same anchor)
  #pragma unroll
  for (int nt=0;nt<2;++nt){
    float om = __shfl_xor(run_m[nt], 32);
    float os = __shfl_xor(run_s[nt], 32);
    float nm = fmaxf(run_m[nt], om);
    float S  = run_s[nt]*__builtin_amdgcn_exp2f(run_m[nt]-nm)
             + os*__builtin_amdgcn_exp2f(om-nm);
    if (half == 0){
      int gm = mb*BMB + wave*BMW + nt*32 + l31;
      part_m[(size_t)gm*NSLOT + ns] = nm;
      part_s[(size_t)gm*NSLOT + ns] = S;
    }
  }
}

// ---------------- Kernel 3: combine partials (one wave per b) ----------------
__global__ __launch_bounds__(256) void combine_kernel(
    const float* __restrict__ part_m, const float* __restrict__ part_s,
    const float* __restrict__ diag, const float* __restrict__ lscale,
    float* __restrict__ infarr){
  int lane = threadIdx.x & 63, wave = threadIdx.x >> 6;
  int b = blockIdx.x*4 + wave;
  float s = lscale[0];
  const float* pm = part_m + (size_t)b*NSLOT;
  const float* ps = part_s + (size_t)b*NSLOT;
  float m = -INFINITY, S = 0.f;
  for (int i = lane; i < NSLOT; i += 64){   // NSLOT=136 >= 2*64: all lanes finite
    float pm_ = pm[i], ps_ = ps[i];
    float nm = fmaxf(m, pm_);
    S = S*__builtin_amdgcn_exp2f(m-nm) + ps_*__builtin_amdgcn_exp2f(pm_-nm);
    m = nm;
  }
  #pragma unroll
  for (int off=1; off<64; off<<=1){
    float om = __shfl_xor(m, off), os = __shfl_xor(S, off);
    float nm = fmaxf(m, om);
    S = S*__builtin_amdgcn_exp2f(m-nm) + os*__builtin_amdgcn_exp2f(om-nm);
    m = nm;
  }
  if (lane == 0)
    infarr[b] = (m + __log2f(S))*LN2 - s*diag[b];   // back to ln domain
}

// ---------------- Kernel 4: final reduction (no atomics) ---------------------
__global__ __launch_bounds__(256) void final_kernel(
    const float* __restrict__ infarr, const float* __restrict__ klarr,
    float* __restrict__ out){
  __shared__ float shi[4], shk[4];
  int tid = threadIdx.x, lane = tid & 63, wave = tid >> 6;
  float inf = 0.f, kl = 0.f;
  for (int i = tid; i < BATCH; i += 256){ inf += infarr[i]; kl += klarr[i]; }
  #pragma unroll
  for (int off=1; off<64; off<<=1){
    inf += __shfl_xor(inf, off);
    kl  += __shfl_xor(kl,  off);
  }
  if (lane == 0){ shi[wave] = inf; shk[wave] = kl; }
  __syncthreads();
  if (tid == 0){
    float I = shi[0]+shi[1]+shi[2]+shi[3];
    float K = shk[0]+shk[1]+shk[2]+shk[3];
    out[0] = BETA*(K*(1.0f/BATCH)) + ALPHA*(I*(1.0f/BATCH));
  }
}

extern "C" void kernel_launch(void* const* d_in, const int* in_sizes, int n_in,
                              void* d_out, int out_size, void* d_ws, size_t ws_size,
                              hipStream_t stream){
  const float* feat   = (const float*)d_in[0];
  const float* scores = (const float*)d_in[1];
  // d_in[2] row_sizes: shape-only, unused
  const float* lscale = (const float*)d_in[3];

  float* ws     = (float*)d_ws;
  float* diag   = ws;                                   // 4096
  float* klarr  = diag + BATCH;                         // 4096
  float* infarr = klarr + BATCH;                        // 4096
  float* part_m = infarr + BATCH;                       // 4096*136
  float* part_s = part_m + (size_t)BATCH*NSLOT;         // 4096*136
  unsigned char* abf8 = (unsigned char*)(part_s + (size_t)BATCH*NSLOT);
  unsigned char* tbf8 = abf8 + (size_t)BATCH*DD;        // 69632*256 fp8, frag-ordered

  prep_kernel<<<BATCH, 256, 0, stream>>>(feat, scores, lscale, abf8, tbf8, diag, klarr);
  gemm_lse_kernel<<<dim3(NSPLIT, MBLK), 256, 0, stream>>>(abf8, tbf8, part_m, part_s);
  combine_kernel<<<BATCH/4, 256, 0, stream>>>(part_m, part_s, diag, lscale, infarr);
  final_kernel<<<1, 256, 0, stream>>>(infarr, klarr, (float*)d_out);
}

// Round 2
// 190.031 us; speedup vs baseline: 1.0773x; 1.0773x over previous
//
#include <hip/hip_runtime.h>
#include <math.h>

#define ALPHA 0.2f
#define BETA 1.0f
#define EPSV 1e-8f
#define LOG2E 1.4426950408889634f
#define LN2 0.6931471805599453f

#define BATCH 4096
#define RR 18
#define KT 17            // R-1 targets per row
#define DD 256
#define NTGT (BATCH*KT)  // 69632 total targets
#define NTILE (NTGT/32)  // 2176 tiles of 32 targets
#define TILE_BYTES (32*DD) // 8192 fp8 bytes per tile, fragment-ordered

#define AG 64            // anchor groups of 64 (one wave each)
#define NSPLIT 32        // N-dimension splits
#define TPS (NTILE/NSPLIT) // 68 tiles per slice
// grid = AG*NSPLIT = 2048 one-wave blocks = full-chip co-residency at 2 waves/SIMD

// Schraudolph fast exp2: 2^d ~= bitcast(u32(d*2^23 + KBIAS)), d<=0.
// v_cvt_u32_f32 saturates negatives to 0 -> free underflow clamp.
#define EXPA 8388608.0f
#define EXPB 1064880320.0f

typedef int   i32x8  __attribute__((ext_vector_type(8)));
typedef float f32x16 __attribute__((ext_vector_type(16)));

__device__ inline int pk8(float a, float b, float c, float d){
  int p = __builtin_amdgcn_cvt_pk_fp8_f32(a, b, 0, false);
  return  __builtin_amdgcn_cvt_pk_fp8_f32(c, d, p, true);
}

__device__ inline float fmax3(float a, float b, float c){
  return fmaxf(fmaxf(a, b), c);   // clang fuses to v_max3_f32
}

__device__ inline float fexp2u(float x, float kc){
  float t = fmaf(x, EXPA, kc);
  unsigned u;
  asm("v_cvt_u32_f32 %0, %1" : "=v"(u) : "v"(t));   // saturating: t<0 -> 0
  return __uint_as_float(u);
}

// tbf8 fragment layout (fp8 e4m3): target t -> tile = t>>5, m = t&31.
// K split: ki=k>>6 (4), hf=(k>>5)&1, w=(k>>4)&1.
// byte addr = tile*8192 + ki*2048 + w*1024 + hf*512 + m*16.
// Gemm lane l (m=l&31, half=l>>5) loads slot (half,m) of regions (ki,0),(ki,1)
// -> 1KB contiguous per (ki,w) across the wave: perfectly coalesced dwordx4.

// ---------------- Kernel 1: convert->fp8 + KL + diag -------------------------
__global__ __launch_bounds__(256) void prep_kernel(
    const float* __restrict__ feat, const float* __restrict__ scores,
    const float* __restrict__ lscale,
    unsigned char* __restrict__ abf8, unsigned char* __restrict__ tbf8,
    float* __restrict__ diag, float* __restrict__ klarr,
    float* __restrict__ out){
  __shared__ float csh[KT];
  int b = blockIdx.x, tid = threadIdx.x;
  int grp = tid >> 4, j = tid & 15;
  const float* fb = feat + (size_t)b * RR * DD;
  float s2 = lscale[0] * LOG2E;

  if (b == 0 && tid == 0) out[0] = 0.f;   // accumulator for fused final reduce

  // anchor: each lane loads its 16 k-values (same across groups -> L1 broadcast)
  float4 a0 = ((const float4*)fb)[j*4+0];
  float4 a1 = ((const float4*)fb)[j*4+1];
  float4 a2 = ((const float4*)fb)[j*4+2];
  float4 a3 = ((const float4*)fb)[j*4+3];
  float asq = (a0.x*a0.x+a0.y*a0.y+a0.z*a0.z+a0.w*a0.w)
            + (a1.x*a1.x+a1.y*a1.y+a1.z*a1.z+a1.w*a1.w)
            + (a2.x*a2.x+a2.y*a2.y+a2.z*a2.z+a2.w*a2.w)
            + (a3.x*a3.x+a3.y*a3.y+a3.z*a3.z+a3.w*a3.w);
  #pragma unroll
  for (int off=1; off<16; off<<=1) asq += __shfl_xor(asq, off);
  float an = fmaxf(sqrtf(asq), EPSV);

  if (tid < 16){   // anchor fp8 out (scaled into log2 domain), 16 B per lane
    uint4 v = make_uint4(
      (unsigned)pk8(a0.x*s2,a0.y*s2,a0.z*s2,a0.w*s2),
      (unsigned)pk8(a1.x*s2,a1.y*s2,a1.z*s2,a1.w*s2),
      (unsigned)pk8(a2.x*s2,a2.y*s2,a2.z*s2,a2.w*s2),
      (unsigned)pk8(a3.x*s2,a3.y*s2,a3.z*s2,a3.w*s2));
    *(uint4*)(abf8 + (size_t)b*DD + j*16) = v;
  }

  for (int kr = grp+1; kr <= KT; kr += 16){
    const float4* tp = (const float4*)(fb + (size_t)kr*DD) + j*4;
    float4 t0=tp[0], t1=tp[1], t2=tp[2], t3=tp[3];
    // fp8 fragment store: lane j holds k in [j*16, j*16+16)
    int t  = b*KT + (kr-1);
    int tile = t >> 5, m = t & 31;
    int ki = j >> 2, hf = (j >> 1) & 1, w = j & 1;
    uint4 v = make_uint4(
      (unsigned)pk8(t0.x,t0.y,t0.z,t0.w), (unsigned)pk8(t1.x,t1.y,t1.z,t1.w),
      (unsigned)pk8(t2.x,t2.y,t2.z,t2.w), (unsigned)pk8(t3.x,t3.y,t3.z,t3.w));
    *(uint4*)(tbf8 + (size_t)tile*TILE_BYTES + ki*2048 + w*1024 + hf*512 + m*16) = v;
    float d = (a0.x*t0.x+a0.y*t0.y+a0.z*t0.z+a0.w*t0.w)
            + (a1.x*t1.x+a1.y*t1.y+a1.z*t1.z+a1.w*t1.w)
            + (a2.x*t2.x+a2.y*t2.y+a2.z*t2.z+a2.w*t2.w)
            + (a3.x*t3.x+a3.y*t3.y+a3.z*t3.z+a3.w*t3.w);
    float q = (t0.x*t0.x+t0.y*t0.y+t0.z*t0.z+t0.w*t0.w)
            + (t1.x*t1.x+t1.y*t1.y+t1.z*t1.z+t1.w*t1.w)
            + (t2.x*t2.x+t2.y*t2.y+t2.z*t2.z+t2.w*t2.w)
            + (t3.x*t3.x+t3.y*t3.y+t3.z*t3.z+t3.w*t3.w);
    #pragma unroll
    for (int off=1; off<16; off<<=1){ d += __shfl_xor(d,off); q += __shfl_xor(q,off); }
    if (j == 0){
      csh[kr-1] = d / (an * fmaxf(sqrtf(q), EPSV));
      if (kr == 1) diag[b] = d;
    }
  }
  __syncthreads();

  // KL over KT=17 entries, wave-parallel on wave 0 (lanes >= KT padded)
  if (tid < 64){
    bool act = tid < KT;
    float c  = act ? csh[tid] : -INFINITY;
    float sv = act ? scores[(size_t)b*KT + tid] : -INFINITY;
    float cm = c, sm = sv;
    #pragma unroll
    for (int off=1; off<64; off<<=1){
      cm = fmaxf(cm, __shfl_xor(cm, off));
      sm = fmaxf(sm, __shfl_xor(sm, off));
    }
    float ec = act ? __builtin_amdgcn_exp2f((c -cm)*LOG2E) : 0.f;
    float es = act ? __builtin_amdgcn_exp2f((sv-sm)*LOG2E) : 0.f;
    float cs = ec, ss = es;
    #pragma unroll
    for (int off=1; off<64; off<<=1){
      cs += __shfl_xor(cs, off);
      ss += __shfl_xor(ss, off);
    }
    float lse_c = cm + __logf(cs);
    float lse_s = sm + __logf(ss);
    float kt = 0.f;
    if (act){
      float lq = sv - lse_s;
      float lp = c  - lse_c;
      kt = __builtin_amdgcn_exp2f(lq*LOG2E)*(lq - lp);
    }
    #pragma unroll
    for (int off=1; off<64; off<<=1) kt += __shfl_xor(kt, off);
    if (tid == 0) klarr[b] = kt * (1.0f/KT);
  }
}

// ---------------- Kernel 2: barrier-free MX-fp8 MFMA + online log2-LSE -------
// One wave per block: 64 anchors x 68 tiles of 32 targets. A-fragments loaded
// direct global->register (coalesced dwordx4, L2-resident via XCD swizzle),
// double-buffered two tiles ahead. No LDS, no barriers: every wave self-paced,
// MFMA phases drift freely across the 2 waves/SIMD; setprio keeps matrix fed.
__global__ __launch_bounds__(64,2) void gemm_lse_kernel(
    const unsigned char* __restrict__ abf8, const unsigned char* __restrict__ tbf8,
    float* __restrict__ part_m, float* __restrict__ part_s){
  const int bid  = blockIdx.x;
  // XCD swizzle (assumes round-robin id%8): ns-octant pinned per XCD so each
  // XCD's L2 holds 4 slices (2.2 MB) + anchors (1 MB).
  const int ns   = (bid & 7)*4 + ((bid >> 3) & 3);
  const int ag   = bid >> 5;
  const int lane = threadIdx.x;
  const int l31  = lane & 31;
  const int half = lane >> 5;

  // anchor B-operand frags: n = nt*32+l31, k = ki*64 + half*32 + [0,32)
  i32x8 af[2][4];
  {
    const unsigned char* ab = abf8 + (size_t)ag*64*DD;
    #pragma unroll
    for (int nt=0;nt<2;++nt)
      #pragma unroll
      for (int ki=0;ki<4;++ki){
        const unsigned char* p = ab + (size_t)(nt*32+l31)*DD + ki*64 + half*32;
        uint4 lo = *(const uint4*)p;
        uint4 hi = *(const uint4*)(p+16);
        af[nt][ki] = (i32x8){(int)lo.x,(int)lo.y,(int)lo.z,(int)lo.w,
                             (int)hi.x,(int)hi.y,(int)hi.z,(int)hi.w};
      }
  }

  const unsigned char* gbase =
      tbf8 + (size_t)(ns*TPS)*TILE_BYTES + half*512 + l31*16;

  i32x8 ta[4], tb[4];
  auto ld = [&](int tt, i32x8 tf[4]){
    const unsigned char* p = gbase + (size_t)tt*TILE_BYTES;
    #pragma unroll
    for (int ki=0;ki<4;++ki){
      uint4 lo = *(const uint4*)(p + ki*2048);
      uint4 hi = *(const uint4*)(p + ki*2048 + 1024);
      tf[ki] = (i32x8){(int)lo.x,(int)lo.y,(int)lo.z,(int)lo.w,
                       (int)hi.x,(int)hi.y,(int)hi.z,(int)hi.w};
    }
  };

  float run_m[2] = {-INFINITY,-INFINITY};
  float run_s[2] = {0.f,0.f};
  f32x16 acc[2];

  auto mfma_tile = [&](i32x8 tf[4]){
    acc[0] = (f32x16)(0.f);
    acc[1] = (f32x16)(0.f);
    __builtin_amdgcn_s_setprio(1);
    #pragma unroll
    for (int ki=0;ki<4;++ki){
      acc[0] = __builtin_amdgcn_mfma_scale_f32_32x32x64_f8f6f4(
                   tf[ki], af[0][ki], acc[0], 0,0, 0,127, 0,127);
      acc[1] = __builtin_amdgcn_mfma_scale_f32_32x32x64_f8f6f4(
                   tf[ki], af[1][ki], acc[1], 0,0, 0,127, 0,127);
    }
    __builtin_amdgcn_s_setprio(0);
  };

  auto epilogue = [&](){
    #pragma unroll
    for (int nt=0;nt<2;++nt){
      f32x16 t = acc[nt];
      float x0 = fmax3(t[0], t[1], t[2]);
      float x1 = fmax3(t[3], t[4], t[5]);
      float x2 = fmax3(t[6], t[7], t[8]);
      float x3 = fmax3(t[9], t[10], t[11]);
      float x4 = fmax3(t[12], t[13], t[14]);
      float mx = fmaxf(fmax3(x0,x1,x2), fmax3(x3,x4,t[15]));

      float kc = fmaf(mx, -EXPA, EXPB);   // fold -mx into Schraudolph bias
      float s0=0.f, s1=0.f, s2=0.f, s3=0.f;
      #pragma unroll
      for (int r=0;r<16;r+=4){
        s0 += fexp2u(t[r  ],kc);
        s1 += fexp2u(t[r+1],kc);
        s2 += fexp2u(t[r+2],kc);
        s3 += fexp2u(t[r+3],kc);
      }
      float sh = (s0+s1)+(s2+s3);

      float nm = fmaxf(run_m[nt], mx);
      run_s[nt] = run_s[nt]*__builtin_amdgcn_exp2f(run_m[nt]-nm)
                + sh*__builtin_amdgcn_exp2f(mx-nm);
      run_m[nt] = nm;
    }
  };

  ld(0, ta);
  ld(1, tb);
  for (int t=0; t<TPS; t+=2){
    mfma_tile(ta);
    if (t+2 < TPS) ld(t+2, ta);   // issue early: hidden under epilogue+next tile
    epilogue();
    mfma_tile(tb);
    if (t+3 < TPS) ld(t+3, tb);
    epilogue();
  }

  // merge the two half-wave partials (disjoint target rows, same anchor col)
  #pragma unroll
  for (int nt=0;nt<2;++nt){
    float om = __shfl_xor(run_m[nt], 32);
    float os = __shfl_xor(run_s[nt], 32);
    float nm = fmaxf(run_m[nt], om);
    float S  = run_s[nt]*__builtin_amdgcn_exp2f(run_m[nt]-nm)
             + os*__builtin_amdgcn_exp2f(om-nm);
    if (half == 0){
      int gm = ag*64 + nt*32 + l31;
      // transposed layout [ns][gm]: 128B coalesced, no cross-block false sharing
      part_m[(size_t)ns*BATCH + gm] = nm;
      part_s[(size_t)ns*BATCH + gm] = S;
    }
  }
}

// ---------------- Kernel 3: combine partials + fused final reduce ------------
__global__ __launch_bounds__(256) void combine_kernel(
    const float* __restrict__ part_m, const float* __restrict__ part_s,
    const float* __restrict__ diag, const float* __restrict__ klarr,
    const float* __restrict__ lscale, float* __restrict__ out){
  int tid = threadIdx.x;
  int b = blockIdx.x*256 + tid;   // grid 16 x 256 = 4096
  float s = lscale[0];
  float m = -INFINITY, S = 0.f;
  #pragma unroll
  for (int ns=0; ns<NSPLIT; ++ns){
    float pm_ = part_m[(size_t)ns*BATCH + b];
    float ps_ = part_s[(size_t)ns*BATCH + b];
    float nm = fmaxf(m, pm_);
    S = S*__builtin_amdgcn_exp2f(m-nm) + ps_*__builtin_amdgcn_exp2f(pm_-nm);
    m = nm;
  }
  float inf = (m + __log2f(S))*LN2 - s*diag[b];   // back to ln domain
  float c = BETA*klarr[b] + ALPHA*inf;
  #pragma unroll
  for (int off=1; off<64; off<<=1) c += __shfl_xor(c, off);
  if ((tid & 63) == 0) atomicAdd(out, c*(1.0f/BATCH));
}

extern "C" void kernel_launch(void* const* d_in, const int* in_sizes, int n_in,
                              void* d_out, int out_size, void* d_ws, size_t ws_size,
                              hipStream_t stream){
  const float* feat   = (const float*)d_in[0];
  const float* scores = (const float*)d_in[1];
  // d_in[2] row_sizes: shape-only, unused
  const float* lscale = (const float*)d_in[3];

  float* ws     = (float*)d_ws;
  float* diag   = ws;                                   // 4096
  float* klarr  = diag + BATCH;                         // 4096
  float* part_m = klarr + BATCH;                        // 32*4096
  float* part_s = part_m + (size_t)NSPLIT*BATCH;        // 32*4096
  unsigned char* abf8 = (unsigned char*)(part_s + (size_t)NSPLIT*BATCH);
  unsigned char* tbf8 = abf8 + (size_t)BATCH*DD;        // 69632*256 fp8, tile-ordered

  float* outp = (float*)d_out;
  prep_kernel<<<BATCH, 256, 0, stream>>>(feat, scores, lscale, abf8, tbf8,
                                         diag, klarr, outp);
  gemm_lse_kernel<<<AG*NSPLIT, 64, 0, stream>>>(abf8, tbf8, part_m, part_s);
  combine_kernel<<<BATCH/256, 256, 0, stream>>>(part_m, part_s, diag, klarr,
                                                lscale, outp);
}

// Round 3
// 187.968 us; speedup vs baseline: 1.0891x; 1.0110x over previous
//
#include <hip/hip_runtime.h>
#include <math.h>

#define ALPHA 0.2f
#define BETA 1.0f
#define EPSV 1e-8f
#define LOG2E 1.4426950408889634f
#define LN2 0.6931471805599453f

#define BATCH 4096
#define RR 18
#define KT 17            // R-1 targets per row
#define DD 256
#define NTGT (BATCH*KT)  // 69632 total targets
#define NTILE (NTGT/32)  // 2176 tiles of 32 targets
#define TILE_BYTES (32*DD) // 8192 fp8 bytes per tile, fragment-ordered

#define AG 16            // anchor groups of 256 (4 waves x 64 anchors)
#define NSPLIT 32        // N-dimension splits
#define TPS (NTILE/NSPLIT) // 68 tiles per slice
#define NRING 4          // LDS ring buffers (32 KB)
// grid = AG*NSPLIT = 512 four-wave blocks = exactly 2 blocks/CU, full co-residency

// Schraudolph fast exp2: 2^d ~= bitcast(u32(d*2^23 + KBIAS)), d<=0.
// v_cvt_u32_f32 saturates negatives to 0 -> free underflow clamp.
#define EXPA 8388608.0f
#define EXPB 1064880320.0f

typedef int   i32x8  __attribute__((ext_vector_type(8)));
typedef float f32x16 __attribute__((ext_vector_type(16)));

__device__ inline void gl_lds16(const void* g, void* l){
  __builtin_amdgcn_global_load_lds(
      (const __attribute__((address_space(1))) unsigned int*)g,
      (__attribute__((address_space(3))) unsigned int*)l, 16, 0, 0);
}

__device__ inline int pk8(float a, float b, float c, float d){
  int p = __builtin_amdgcn_cvt_pk_fp8_f32(a, b, 0, false);
  return  __builtin_amdgcn_cvt_pk_fp8_f32(c, d, p, true);
}

__device__ inline float fmax3(float a, float b, float c){
  return fmaxf(fmaxf(a, b), c);   // clang fuses to v_max3_f32
}

__device__ inline float fexp2u(float x, float kc){
  float t = fmaf(x, EXPA, kc);
  unsigned u;
  asm("v_cvt_u32_f32 %0, %1" : "=v"(u) : "v"(t));   // saturating: t<0 -> 0
  return __uint_as_float(u);
}

// tbf8 fragment layout (fp8 e4m3): target t -> tile = t>>5, m = t&31.
// K split: ki=k>>6 (4), hf=(k>>5)&1, w=(k>>4)&1.
// byte addr = tile*8192 + ki*2048 + w*1024 + hf*512 + m*16.
// Gemm lane l (m=l&31, half=l>>5) reads slot (half,m) of regions (ki,0),(ki,1)
// -> per ds_read_b128 the 64 lanes cover one contiguous 1KB region: conflict-free.

// ---------------- Kernel 1: convert->fp8 + KL + diag -------------------------
__global__ __launch_bounds__(256) void prep_kernel(
    const float* __restrict__ feat, const float* __restrict__ scores,
    const float* __restrict__ lscale,
    unsigned char* __restrict__ abf8, unsigned char* __restrict__ tbf8,
    float* __restrict__ diag, float* __restrict__ klarr,
    float* __restrict__ out){
  __shared__ float csh[KT];
  int b = blockIdx.x, tid = threadIdx.x;
  int grp = tid >> 4, j = tid & 15;
  const float* fb = feat + (size_t)b * RR * DD;
  float s2 = lscale[0] * LOG2E;

  if (b == 0 && tid == 0) out[0] = 0.f;   // accumulator for fused final reduce

  // anchor: each lane loads its 16 k-values (same across groups -> L1 broadcast)
  float4 a0 = ((const float4*)fb)[j*4+0];
  float4 a1 = ((const float4*)fb)[j*4+1];
  float4 a2 = ((const float4*)fb)[j*4+2];
  float4 a3 = ((const float4*)fb)[j*4+3];
  float asq = (a0.x*a0.x+a0.y*a0.y+a0.z*a0.z+a0.w*a0.w)
            + (a1.x*a1.x+a1.y*a1.y+a1.z*a1.z+a1.w*a1.w)
            + (a2.x*a2.x+a2.y*a2.y+a2.z*a2.z+a2.w*a2.w)
            + (a3.x*a3.x+a3.y*a3.y+a3.z*a3.z+a3.w*a3.w);
  #pragma unroll
  for (int off=1; off<16; off<<=1) asq += __shfl_xor(asq, off);
  float an = fmaxf(sqrtf(asq), EPSV);

  if (tid < 16){   // anchor fp8 out (scaled into log2 domain), 16 B per lane
    uint4 v = make_uint4(
      (unsigned)pk8(a0.x*s2,a0.y*s2,a0.z*s2,a0.w*s2),
      (unsigned)pk8(a1.x*s2,a1.y*s2,a1.z*s2,a1.w*s2),
      (unsigned)pk8(a2.x*s2,a2.y*s2,a2.z*s2,a2.w*s2),
      (unsigned)pk8(a3.x*s2,a3.y*s2,a3.z*s2,a3.w*s2));
    *(uint4*)(abf8 + (size_t)b*DD + j*16) = v;
  }

  for (int kr = grp+1; kr <= KT; kr += 16){
    const float4* tp = (const float4*)(fb + (size_t)kr*DD) + j*4;
    float4 t0=tp[0], t1=tp[1], t2=tp[2], t3=tp[3];
    // fp8 fragment store: lane j holds k in [j*16, j*16+16)
    int t  = b*KT + (kr-1);
    int tile = t >> 5, m = t & 31;
    int ki = j >> 2, hf = (j >> 1) & 1, w = j & 1;
    uint4 v = make_uint4(
      (unsigned)pk8(t0.x,t0.y,t0.z,t0.w), (unsigned)pk8(t1.x,t1.y,t1.z,t1.w),
      (unsigned)pk8(t2.x,t2.y,t2.z,t2.w), (unsigned)pk8(t3.x,t3.y,t3.z,t3.w));
    *(uint4*)(tbf8 + (size_t)tile*TILE_BYTES + ki*2048 + w*1024 + hf*512 + m*16) = v;
    float d = (a0.x*t0.x+a0.y*t0.y+a0.z*t0.z+a0.w*t0.w)
            + (a1.x*t1.x+a1.y*t1.y+a1.z*t1.z+a1.w*t1.w)
            + (a2.x*t2.x+a2.y*t2.y+a2.z*t2.z+a2.w*t2.w)
            + (a3.x*t3.x+a3.y*t3.y+a3.z*t3.z+a3.w*t3.w);
    float q = (t0.x*t0.x+t0.y*t0.y+t0.z*t0.z+t0.w*t0.w)
            + (t1.x*t1.x+t1.y*t1.y+t1.z*t1.z+t1.w*t1.w)
            + (t2.x*t2.x+t2.y*t2.y+t2.z*t2.z+t2.w*t2.w)
            + (t3.x*t3.x+t3.y*t3.y+t3.z*t3.z+t3.w*t3.w);
    #pragma unroll
    for (int off=1; off<16; off<<=1){ d += __shfl_xor(d,off); q += __shfl_xor(q,off); }
    if (j == 0){
      csh[kr-1] = d / (an * fmaxf(sqrtf(q), EPSV));
      if (kr == 1) diag[b] = d;
    }
  }
  __syncthreads();

  // KL over KT=17 entries, wave-parallel on wave 0 (lanes >= KT padded)
  if (tid < 64){
    bool act = tid < KT;
    float c  = act ? csh[tid] : -INFINITY;
    float sv = act ? scores[(size_t)b*KT + tid] : -INFINITY;
    float cm = c, sm = sv;
    #pragma unroll
    for (int off=1; off<64; off<<=1){
      cm = fmaxf(cm, __shfl_xor(cm, off));
      sm = fmaxf(sm, __shfl_xor(sm, off));
    }
    float ec = act ? __builtin_amdgcn_exp2f((c -cm)*LOG2E) : 0.f;
    float es = act ? __builtin_amdgcn_exp2f((sv-sm)*LOG2E) : 0.f;
    float cs = ec, ss = es;
    #pragma unroll
    for (int off=1; off<64; off<<=1){
      cs += __shfl_xor(cs, off);
      ss += __shfl_xor(ss, off);
    }
    float lse_c = cm + __logf(cs);
    float lse_s = sm + __logf(ss);
    float kt = 0.f;
    if (act){
      float lq = sv - lse_s;
      float lp = c  - lse_c;
      kt = __builtin_amdgcn_exp2f(lq*LOG2E)*(lq - lp);
    }
    #pragma unroll
    for (int off=1; off<64; off<<=1) kt += __shfl_xor(kt, off);
    if (tid == 0) klarr[b] = kt * (1.0f/KT);
  }
}

// ---------------- Kernel 2: LDS-shared MX-fp8 MFMA + online log2-LSE ---------
// 4 waves x 64 anchors per block share one tile stream staged via
// global_load_lds into a 4-deep LDS ring. Counted vmcnt(2) + raw s_barrier:
// one prefetch tile always stays in flight (no vmcnt(0) drain in the loop).
// Double-buffered accumulators: epilogue of tile t overlaps MFMAs of tile t+1.
// The 4 waves sit on 4 different SIMDs, so each SIMD pairs waves from two
// DIFFERENT blocks -> barriers never align the waves sharing a matrix pipe.
__global__ __launch_bounds__(256,2) void gemm_lse_kernel(
    const unsigned char* __restrict__ abf8, const unsigned char* __restrict__ tbf8,
    float* __restrict__ part_m, float* __restrict__ part_s){
  __shared__ __align__(16) unsigned char Bs[NRING][TILE_BYTES];   // 32 KB
  const int bid  = blockIdx.x;
  // XCD swizzle (round-robin id%8): 4 ns slices pinned per XCD ->
  // per-XCD L2 holds 2.2 MB of tbf8 + 1 MB anchors.
  const int ns   = (bid & 7)*4 + ((bid >> 3) & 3);
  const int ag   = bid >> 5;
  const int tid  = threadIdx.x;
  const int lane = tid & 63;
  const int wave = tid >> 6;
  const int l31  = lane & 31;
  const int half = lane >> 5;

  const unsigned char* gbase = tbf8 + (size_t)(ns*TPS)*TILE_BYTES;
  auto stage = [&](int t){
    const unsigned char* g = gbase + (size_t)t*TILE_BYTES;
    unsigned char* l = &Bs[t & (NRING-1)][0];
    #pragma unroll
    for (int jj=0;jj<2;++jj){
      int off = jj*4096 + tid*16;
      gl_lds16(g + off, l + off);
    }
  };

  stage(0);
  stage(1);

  // anchor B-operand frags: n = nt*32+l31, k = ki*64 + half*32 + [0,32)
  i32x8 af[2][4];
  {
    const unsigned char* ab = abf8 + (size_t)(ag*256 + wave*64)*DD;
    #pragma unroll
    for (int nt=0;nt<2;++nt)
      #pragma unroll
      for (int ki=0;ki<4;++ki){
        const unsigned char* p = ab + (size_t)(nt*32+l31)*DD + ki*64 + half*32;
        uint4 lo = *(const uint4*)p;
        uint4 hi = *(const uint4*)(p+16);
        af[nt][ki] = (i32x8){(int)lo.x,(int)lo.y,(int)lo.z,(int)lo.w,
                             (int)hi.x,(int)hi.y,(int)hi.z,(int)hi.w};
      }
  }

  float run_m[2] = {-INFINITY,-INFINITY};
  float run_s[2] = {0.f,0.f};
  f32x16 accA[2], accB[2];
  #pragma unroll
  for (int nt=0;nt<2;++nt){ accA[nt]=(f32x16)(0.f); accB[nt]=(f32x16)(0.f); }

  // wait for tile t's DMA (leave the prefetch in flight), rendezvous, stage t+2,
  // ds_read tile t, MFMA into acc. Compiler schedules the caller's epilogue
  // (independent VALU) into the ds_read/MFMA latency shadows.
  auto mfma_tile = [&](int t, f32x16 (&acc)[2], bool last){
    if (last) asm volatile("s_waitcnt vmcnt(0)" ::: "memory");
    else      asm volatile("s_waitcnt vmcnt(2)" ::: "memory");
    __builtin_amdgcn_s_barrier();
    asm volatile("" ::: "memory");
    if (t+2 < TPS) stage(t+2);

    const unsigned char* fb = &Bs[t & (NRING-1)][0] + half*512 + l31*16;
    i32x8 tf[4];
    #pragma unroll
    for (int ki=0;ki<4;++ki){
      uint4 lo = *(const uint4*)(fb + ki*2048);
      uint4 hi = *(const uint4*)(fb + ki*2048 + 1024);
      tf[ki] = (i32x8){(int)lo.x,(int)lo.y,(int)lo.z,(int)lo.w,
                       (int)hi.x,(int)hi.y,(int)hi.z,(int)hi.w};
    }
    __builtin_amdgcn_s_setprio(1);
    #pragma unroll
    for (int ki=0;ki<4;++ki){
      acc[0] = __builtin_amdgcn_mfma_scale_f32_32x32x64_f8f6f4(
                   tf[ki], af[0][ki], acc[0], 0,0, 0,127, 0,127);
      acc[1] = __builtin_amdgcn_mfma_scale_f32_32x32x64_f8f6f4(
                   tf[ki], af[1][ki], acc[1], 0,0, 0,127, 0,127);
    }
    __builtin_amdgcn_s_setprio(0);
  };

  auto epilogue = [&](f32x16 (&acc)[2]){
    #pragma unroll
    for (int nt=0;nt<2;++nt){
      f32x16 t = acc[nt];
      float x0 = fmax3(t[0], t[1], t[2]);
      float x1 = fmax3(t[3], t[4], t[5]);
      float x2 = fmax3(t[6], t[7], t[8]);
      float x3 = fmax3(t[9], t[10], t[11]);
      float x4 = fmax3(t[12], t[13], t[14]);
      float mx = fmaxf(fmax3(x0,x1,x2), fmax3(x3,x4,t[15]));

      float kc = fmaf(mx, -EXPA, EXPB);   // fold -mx into Schraudolph bias
      float s0=0.f, s1=0.f, s2=0.f, s3=0.f;
      #pragma unroll
      for (int r=0;r<16;r+=4){
        s0 += fexp2u(t[r  ],kc);
        s1 += fexp2u(t[r+1],kc);
        s2 += fexp2u(t[r+2],kc);
        s3 += fexp2u(t[r+3],kc);
      }
      float sh = (s0+s1)+(s2+s3);

      float nm = fmaxf(run_m[nt], mx);
      run_s[nt] = run_s[nt]*__builtin_amdgcn_exp2f(run_m[nt]-nm)
                + sh*__builtin_amdgcn_exp2f(mx-nm);
      run_m[nt] = nm;
      acc[nt] = (f32x16)(0.f);   // ready for reuse two tiles later
    }
  };

  mfma_tile(0, accA, false);
  for (int t=1; t+1 < TPS; t+=2){   // t = 1,3,...,65 -> tiles 1..66
    mfma_tile(t,   accB, false);
    epilogue(accA);                 // tile t-1, overlaps accB MFMAs
    mfma_tile(t+1, accA, false);
    epilogue(accB);                 // tile t
  }
  mfma_tile(TPS-1, accB, true);     // tile 67, drain last DMA
  epilogue(accA);                   // tile 66
  epilogue(accB);                   // tile 67

  // merge the two half-wave partials (disjoint target rows, same anchor col)
  #pragma unroll
  for (int nt=0;nt<2;++nt){
    float om = __shfl_xor(run_m[nt], 32);
    float os = __shfl_xor(run_s[nt], 32);
    float nm = fmaxf(run_m[nt], om);
    float S  = run_s[nt]*__builtin_amdgcn_exp2f(run_m[nt]-nm)
             + os*__builtin_amdgcn_exp2f(om-nm);
    if (half == 0){
      int gm = ag*256 + wave*64 + nt*32 + l31;
      // transposed layout [ns][gm]: 128B coalesced, no cross-block false sharing
      part_m[(size_t)ns*BATCH + gm] = nm;
      part_s[(size_t)ns*BATCH + gm] = S;
    }
  }
}

// ---------------- Kernel 3: combine partials + fused final reduce ------------
__global__ __launch_bounds__(256) void combine_kernel(
    const float* __restrict__ part_m, const float* __restrict__ part_s,
    const float* __restrict__ diag, const float* __restrict__ klarr,
    const float* __restrict__ lscale, float* __restrict__ out){
  int tid = threadIdx.x;
  int b = blockIdx.x*256 + tid;   // grid 16 x 256 = 4096
  float s = lscale[0];
  float m = -INFINITY, S = 0.f;
  #pragma unroll
  for (int ns=0; ns<NSPLIT; ++ns){
    float pm_ = part_m[(size_t)ns*BATCH + b];
    float ps_ = part_s[(size_t)ns*BATCH + b];
    float nm = fmaxf(m, pm_);
    S = S*__builtin_amdgcn_exp2f(m-nm) + ps_*__builtin_amdgcn_exp2f(pm_-nm);
    m = nm;
  }
  float inf = (m + __log2f(S))*LN2 - s*diag[b];   // back to ln domain
  float c = BETA*klarr[b] + ALPHA*inf;
  #pragma unroll
  for (int off=1; off<64; off<<=1) c += __shfl_xor(c, off);
  if ((tid & 63) == 0) atomicAdd(out, c*(1.0f/BATCH));
}

extern "C" void kernel_launch(void* const* d_in, const int* in_sizes, int n_in,
                              void* d_out, int out_size, void* d_ws, size_t ws_size,
                              hipStream_t stream){
  const float* feat   = (const float*)d_in[0];
  const float* scores = (const float*)d_in[1];
  // d_in[2] row_sizes: shape-only, unused
  const float* lscale = (const float*)d_in[3];

  float* ws     = (float*)d_ws;
  float* diag   = ws;                                   // 4096
  float* klarr  = diag + BATCH;                         // 4096
  float* part_m = klarr + BATCH;                        // 32*4096
  float* part_s = part_m + (size_t)NSPLIT*BATCH;        // 32*4096
  unsigned char* abf8 = (unsigned char*)(part_s + (size_t)NSPLIT*BATCH);
  unsigned char* tbf8 = abf8 + (size_t)BATCH*DD;        // 69632*256 fp8, tile-ordered

  float* outp = (float*)d_out;
  prep_kernel<<<BATCH, 256, 0, stream>>>(feat, scores, lscale, abf8, tbf8,
                                         diag, klarr, outp);
  gemm_lse_kernel<<<AG*NSPLIT, 256, 0, stream>>>(abf8, tbf8, part_m, part_s);
  combine_kernel<<<BATCH/256, 256, 0, stream>>>(part_m, part_s, diag, klarr,
                                                lscale, outp);
}